// Round 8
// baseline (342.715 us; speedup 1.0000x reference)
//
#include <hip/hip_runtime.h>
#include <hip/hip_bf16.h>

#define E 8
#define D 2048
#define H 8192
#define R 64
#define NTOK 4096
#define HSPLIT 4
#define HPER (H / HSPLIT)   // 2048
#define MSLOT 128           // slots per mid block

typedef __attribute__((ext_vector_type(8))) short bf16x8;
typedef __attribute__((ext_vector_type(4))) float f32x4;
typedef __attribute__((ext_vector_type(16))) float f32x16;

__device__ __forceinline__ unsigned short f2b(float f){
  union { __hip_bfloat16 h; unsigned short u; } cv;
  cv.h = __float2bfloat16(f);
  return cv.u;
}
__device__ __forceinline__ float b2f(unsigned short u){
  union { unsigned int i; float f; } cv; cv.i = ((unsigned int)u) << 16; return cv.f;
}

// MFMA 16x16x32 fragment from [row][k] LDS tile
__device__ __forceinline__ bf16x8 ldfrag(const unsigned short* base, int row0, int k0,
                                         int pitch, int lane){
  return *reinterpret_cast<const bf16x8*>(base + (row0 + (lane & 15)) * pitch
                                          + k0 + ((lane >> 4) << 3));
}
// MFMA 32x32x16 fragment from [row][k] LDS tile: lane l -> row row0+(l&31), k k0+(l>>5)*8..+7
__device__ __forceinline__ bf16x8 ldfrag32(const unsigned short* base, int row0, int k0,
                                           int pitch, int lane){
  return *reinterpret_cast<const bf16x8*>(base + (row0 + (lane & 31)) * pitch
                                          + k0 + ((lane >> 5) << 3));
}

// ---------------- transpose-pack: src[e][RS][CS] f32 -> dst[e][CS][RS] bf16 ----------------
__global__ __launch_bounds__(256) void pack_tr(const float* __restrict__ src,
                                               unsigned short* __restrict__ dst,
                                               int RS, int CS){
  int e = blockIdx.z;
  const float* s = src + (size_t)e * RS * CS;
  unsigned short* d = dst + (size_t)e * RS * CS;
  int c0 = blockIdx.x * 64, r0 = blockIdx.y * 64;
  int l = threadIdx.x & 63, cb = (threadIdx.x >> 6) * 16;
  int r = r0 + l;
  const float4* sp = reinterpret_cast<const float4*>(s + (size_t)r * CS + c0 + cb);
  float v[16];
  #pragma unroll
  for (int q = 0; q < 4; ++q){
    float4 t = sp[q];
    v[q*4] = t.x; v[q*4+1] = t.y; v[q*4+2] = t.z; v[q*4+3] = t.w;
  }
  #pragma unroll
  for (int j = 0; j < 16; ++j)
    d[(size_t)(c0 + cb + j) * RS + r] = f2b(v[j]);
}

// ---------------- gate: NO ATOMICS. logits + top2 + weights -> tsl; fused xb pack ----------------
__global__ __launch_bounds__(256) void gate_kernel(
    const float* __restrict__ x, const float* __restrict__ gw,
    const float* __restrict__ gb, int* __restrict__ tsl,
    unsigned short* __restrict__ xb)
{
  int wid  = threadIdx.x >> 6;
  int lane = threadIdx.x & 63;
  int n0 = blockIdx.x * 8 + wid * 2;      // 2 tokens per wave

  float acc[2][E];
  #pragma unroll
  for (int t = 0; t < 2; ++t)
    #pragma unroll
    for (int e = 0; e < E; ++e) acc[t][e] = 0.f;

  for (int i = 0; i < D / 256; ++i){      // 8 iters
    int dd = i * 256 + lane * 4;
    float4 xv[2];
    #pragma unroll
    for (int t = 0; t < 2; ++t){
      xv[t] = *reinterpret_cast<const float4*>(x + (size_t)(n0 + t) * D + dd);
      unsigned short o[4] = { f2b(xv[t].x), f2b(xv[t].y), f2b(xv[t].z), f2b(xv[t].w) };
      *reinterpret_cast<ushort4*>(xb + (size_t)(n0 + t) * D + dd) = *reinterpret_cast<ushort4*>(o);
    }
    #pragma unroll
    for (int e = 0; e < E; ++e){
      float4 g = *reinterpret_cast<const float4*>(gw + (size_t)e * D + dd);
      #pragma unroll
      for (int t = 0; t < 2; ++t)
        acc[t][e] += xv[t].x * g.x + xv[t].y * g.y + xv[t].z * g.z + xv[t].w * g.w;
    }
  }

  #pragma unroll
  for (int t = 0; t < 2; ++t){
    #pragma unroll
    for (int e = 0; e < E; ++e){
      float v = acc[t][e];
      for (int off = 32; off; off >>= 1) v += __shfl_xor(v, off, 64);
      acc[t][e] = v + gb[e];
    }
    if (lane == 0){
      int n = n0 + t;
      float l0 = -1e30f, l1 = -1e30f; int i0 = 0, i1 = 0;
      #pragma unroll
      for (int e = 0; e < E; ++e){
        float v = acc[t][e];
        if (v > l0){ l1 = l0; i1 = i0; l0 = v; i0 = e; }
        else if (v > l1){ l1 = v; i1 = e; }
      }
      float tt = expf(l1 - l0);
      float w0 = 1.f / (1.f + tt);
      float w1 = tt * w0;
      int* ts = tsl + n * 8;
      ts[0] = i0; ts[2] = __float_as_int(w0);
      ts[3] = i1; ts[5] = __float_as_int(w1);
    }
  }
}

// ---------------- route: wave-aggregated slot assignment (512 atomics total) ----------------
__global__ __launch_bounds__(256) void route_kernel(
    int* __restrict__ tsl, int* __restrict__ cnt, int* __restrict__ lst)
{
  int wid  = threadIdx.x >> 6;
  int lane = threadIdx.x & 63;
  int tok  = blockIdx.x * 256 + wid * 64 + lane;
  int* ts = tsl + tok * 8;
  int i0 = ts[0], i1 = ts[3];
  unsigned long long below = (1ULL << lane) - 1ULL;

  #pragma unroll
  for (int e = 0; e < E; ++e){
    unsigned long long m0 = __ballot(i0 == e);
    unsigned long long m1 = __ballot(i1 == e);
    int c0  = __popcll(m0);
    int tot = c0 + __popcll(m1);
    int base = 0;
    if (lane == 0 && tot) base = atomicAdd(&cnt[e], tot);
    base = __shfl(base, 0, 64);
    if (i0 == e){
      int p = base + __popcll(m0 & below);
      lst[e * NTOK + p] = tok;  ts[1] = p;
    }
    if (i1 == e){
      int p = base + c0 + __popcll(m1 & below);
      lst[e * NTOK + p] = tok;  ts[4] = p;
    }
  }
}

// ---------------- T1 = X_gather @ u1[e]  (64-slot tile, 256 thr) ----------------
__global__ __launch_bounds__(256) void t1_kernel(
    const unsigned short* __restrict__ xb, const unsigned short* __restrict__ u1p,
    const int* __restrict__ cnt, const int* __restrict__ lst,
    unsigned short* __restrict__ T1buf)
{
  int e = blockIdx.y;
  int nc = cnt[e];
  int t0 = blockIdx.x * 64;
  if (t0 >= nc) return;

  __shared__ int s_tok[64];
  __shared__ unsigned short Xs[64 * 136];
  __shared__ unsigned short U1s[64 * 136];
  int tid = threadIdx.x, w = tid >> 6, lane = tid & 63;

  if (tid < 64) s_tok[tid] = lst[e * NTOK + min(t0 + tid, nc - 1)];
  __syncthreads();

  int m = (w & 3) * 16;
  f32x4 z = {0.f, 0.f, 0.f, 0.f};
  f32x4 acc[4] = {z, z, z, z};

  for (int kc = 0; kc < D; kc += 128){
    __syncthreads();
    #pragma unroll
    for (int s = 0; s < 4; ++s){
      int id = tid + s * 256;
      int rr = id >> 4, c = (id & 15) * 8;
      *reinterpret_cast<bf16x8*>(&Xs[rr * 136 + c]) =
        *reinterpret_cast<const bf16x8*>(&xb[(size_t)s_tok[rr] * D + kc + c]);
      *reinterpret_cast<bf16x8*>(&U1s[rr * 136 + c]) =
        *reinterpret_cast<const bf16x8*>(&u1p[((size_t)e * R + rr) * D + kc + c]);
    }
    __syncthreads();
    #pragma unroll
    for (int j = 0; j < 4; ++j)
      #pragma unroll
      for (int ks = 0; ks < 4; ++ks)
        acc[j] = __builtin_amdgcn_mfma_f32_16x16x32_bf16(
            ldfrag(Xs, m, ks * 32, 136, lane),
            ldfrag(U1s, j * 16, ks * 32, 136, lane), acc[j], 0, 0, 0);
  }
  #pragma unroll
  for (int j = 0; j < 4; ++j){
    int col = j * 16 + (lane & 15);
    #pragma unroll
    for (int q = 0; q < 4; ++q){
      int row = m + ((lane >> 4) << 2) + q;
      T1buf[((size_t)e * NTOK + t0 + row) * R + col] = f2b(acc[j][q]);
    }
  }
}

// ---------------- mid v3: 32x32x16 MFMA, 128 slots, register-blocked ----------------
// T2 += relu(T1 @ v1 + b1) @ u2 over H/4. LDS ~95 KiB -> 1 block/CU, 8 waves.
__global__ __launch_bounds__(512, 2) void mid_kernel(
    const unsigned short* __restrict__ T1buf, const unsigned short* __restrict__ v1p,
    const unsigned short* __restrict__ u2p, const float* __restrict__ b1,
    const int* __restrict__ cnt, float* __restrict__ T2acc)
{
  int e = blockIdx.z;
  int nc = cnt[e];
  int t0 = blockIdx.x * MSLOT;
  if (t0 >= nc) return;
  int hc0 = blockIdx.y * HPER;

  __shared__ unsigned short T1s[MSLOT * 72];   // [slot][r]
  __shared__ unsigned short v1s[128 * 72];     // [h][r] subchunk
  __shared__ unsigned short u2s[64 * 136];     // [r][h] subchunk
  __shared__ unsigned short Hs[MSLOT * 136];   // [slot][h] subchunk
  __shared__ float b1s[HPER];

  int tid = threadIdx.x, w = tid >> 6, lane = tid & 63;

  #pragma unroll
  for (int s = 0; s < 2; ++s){                 // T1s: 128x64 = 1024 vec8
    int id = tid + s * 512;
    int rr = id >> 3, c = (id & 7) * 8;
    *reinterpret_cast<bf16x8*>(&T1s[rr * 72 + c]) =
      *reinterpret_cast<const bf16x8*>(&T1buf[((size_t)e * NTOK + t0 + rr) * R + c]);
  }
  for (int i = tid; i < HPER; i += 512) b1s[i] = b1[(size_t)e * H + hc0 + i];

  // wave maps
  int mB = (w & 3) * 32;        // slot group (B1 and B2)
  int nB = (w >> 2) * 64;       // B1: two 32-wide h tiles
  int kh = (w >> 2) * 64;       // B2: k-half of the 128-h subchunk

  f32x16 acc0, acc1;            // B2 accumulators: [slots 32] x [r 0..31], [r 32..63]
  #pragma unroll
  for (int q = 0; q < 16; ++q){ acc0[q] = 0.f; acc1[q] = 0.f; }

  // register prefetch of subchunk 0 (T14)
  bf16x8 pv[2], pu[2];
  #pragma unroll
  for (int s = 0; s < 2; ++s){
    int id = tid + s * 512;
    pv[s] = *reinterpret_cast<const bf16x8*>(&v1p[((size_t)e * H + hc0 + (id >> 3)) * R + (id & 7) * 8]);
    pu[s] = *reinterpret_cast<const bf16x8*>(&u2p[((size_t)e * R + (id >> 4)) * H + hc0 + (id & 15) * 8]);
  }

  for (int hs = 0; hs < HPER; hs += 128){
    __syncthreads();                           // prev iter done reading v1s/u2s/Hs
    #pragma unroll
    for (int s = 0; s < 2; ++s){
      int id = tid + s * 512;
      *reinterpret_cast<bf16x8*>(&v1s[(id >> 3) * 72 + (id & 7) * 8]) = pv[s];
      *reinterpret_cast<bf16x8*>(&u2s[(id >> 4) * 136 + (id & 15) * 8]) = pu[s];
    }
    __syncthreads();

    // B1: Hs[mB..+31][nB..+63] = relu(T1 @ v1 + b1)
    f32x16 h0, h1;
    #pragma unroll
    for (int q = 0; q < 16; ++q){ h0[q] = 0.f; h1[q] = 0.f; }
    #pragma unroll
    for (int kc = 0; kc < 4; ++kc){            // K = R = 64
      bf16x8 a = ldfrag32(T1s, mB, kc * 16, 72, lane);
      h0 = __builtin_amdgcn_mfma_f32_32x32x16_bf16(
          a, ldfrag32(v1s, nB, kc * 16, 72, lane), h0, 0, 0, 0);
      h1 = __builtin_amdgcn_mfma_f32_32x32x16_bf16(
          a, ldfrag32(v1s, nB + 32, kc * 16, 72, lane), h1, 0, 0, 0);
    }
    {
      int c0 = nB + (lane & 31);
      float bv0 = b1s[hs + c0], bv1 = b1s[hs + c0 + 32];
      #pragma unroll
      for (int q = 0; q < 16; ++q){
        int srow = mB + (q & 3) + 8 * (q >> 2) + 4 * (lane >> 5);
        float v0 = h0[q] + bv0, v1v = h1[q] + bv1;
        Hs[srow * 136 + c0]      = f2b(v0 > 0.f ? v0 : 0.f);
        Hs[srow * 136 + c0 + 32] = f2b(v1v > 0.f ? v1v : 0.f);
      }
    }
    // prefetch next subchunk (overlaps barrier + B2)
    int hn = (hs + 128 < HPER) ? hs + 128 : 0;
    #pragma unroll
    for (int s = 0; s < 2; ++s){
      int id = tid + s * 512;
      pv[s] = *reinterpret_cast<const bf16x8*>(&v1p[((size_t)e * H + hc0 + hn + (id >> 3)) * R + (id & 7) * 8]);
      pu[s] = *reinterpret_cast<const bf16x8*>(&u2p[((size_t)e * R + (id >> 4)) * H + hc0 + hn + (id & 15) * 8]);
    }
    __syncthreads();                           // Hs visible

    // B2: acc += Hs[mB][kh..+63] @ u2^T
    #pragma unroll
    for (int kc = 0; kc < 4; ++kc){
      bf16x8 a = ldfrag32(Hs, mB, kh + kc * 16, 136, lane);
      acc0 = __builtin_amdgcn_mfma_f32_32x32x16_bf16(
          a, ldfrag32(u2s, 0,  kh + kc * 16, 136, lane), acc0, 0, 0, 0);
      acc1 = __builtin_amdgcn_mfma_f32_32x32x16_bf16(
          a, ldfrag32(u2s, 32, kh + kc * 16, 136, lane), acc1, 0, 0, 0);
    }
  }

  int col = lane & 31;
  #pragma unroll
  for (int q = 0; q < 16; ++q){
    int srow = mB + (q & 3) + 8 * (q >> 2) + 4 * (lane >> 5);
    float* dst = &T2acc[((size_t)e * NTOK + t0 + srow) * R];
    atomicAdd(dst + col,      acc0[q]);
    atomicAdd(dst + col + 32, acc1[q]);
  }
}

// ---------------- out: y[slot] = T2 @ v2[e] + b2  -> compact bf16 yb ----------------
__global__ __launch_bounds__(512, 4) void out_kernel(
    const float* __restrict__ T2acc, const unsigned short* __restrict__ v2p,
    const float* __restrict__ b2, const int* __restrict__ cnt,
    unsigned short* __restrict__ yb)
{
  int e = blockIdx.y;
  int nc = cnt[e];
  int t0 = blockIdx.x * 64;
  if (t0 >= nc) return;
  int base = 0;
  #pragma unroll
  for (int i = 0; i < E; ++i) base += (i < e) ? cnt[i] : 0;

  __shared__ unsigned short T2s[64 * 72];
  __shared__ unsigned short v2s[256 * 72];
  __shared__ float b2s[D];
  int tid = threadIdx.x, w = tid >> 6, lane = tid & 63;

  { int rr = tid >> 3, c = (tid & 7) * 8;
    const float* src = &T2acc[((size_t)e * NTOK + t0 + rr) * R + c];
    float4 a = *reinterpret_cast<const float4*>(src);
    float4 b = *reinterpret_cast<const float4*>(src + 4);
    unsigned short o[8] = { f2b(a.x), f2b(a.y), f2b(a.z), f2b(a.w),
                            f2b(b.x), f2b(b.y), f2b(b.z), f2b(b.w) };
    *reinterpret_cast<bf16x8*>(&T2s[rr * 72 + c]) = *reinterpret_cast<bf16x8*>(o); }
  for (int i = tid; i < D; i += 512) b2s[i] = b2[(size_t)e * D + i];

  int m1 = (w & 1) * 32, nb = (w >> 1) * 64;
  f32x4 z = {0.f, 0.f, 0.f, 0.f};

  for (int dc = 0; dc < D; dc += 256){
    __syncthreads();
    #pragma unroll
    for (int s = 0; s < 4; ++s){
      int id = tid + s * 512;
      int rr = id >> 3, c = (id & 7) * 8;
      *reinterpret_cast<bf16x8*>(&v2s[rr * 72 + c]) =
        *reinterpret_cast<const bf16x8*>(&v2p[((size_t)e * D + dc + rr) * R + c]);
    }
    __syncthreads();
    #pragma unroll
    for (int i = 0; i < 2; ++i)
      #pragma unroll
      for (int j = 0; j < 4; ++j){
        f32x4 a = z;
        #pragma unroll
        for (int ks = 0; ks < 2; ++ks)
          a = __builtin_amdgcn_mfma_f32_16x16x32_bf16(
              ldfrag(T2s, m1 + i * 16, ks * 32, 72, lane),
              ldfrag(v2s, nb + j * 16, ks * 32, 72, lane), a, 0, 0, 0);
        int dcol = dc + nb + j * 16 + (lane & 15);
        float bv = b2s[dcol];
        #pragma unroll
        for (int q = 0; q < 4; ++q){
          int row = m1 + i * 16 + ((lane >> 4) << 2) + q;
          if (t0 + row < nc)
            yb[((size_t)(base + t0 + row)) * D + dcol] = f2b(a[q] + bv);
        }
      }
  }
}

// ---------------- combine: out[tok] = w0*y[g0] + w1*y[g1] ----------------
__global__ __launch_bounds__(256) void combine_kernel(
    const unsigned short* __restrict__ yb, const int* __restrict__ tsl,
    const int* __restrict__ cnt, float* __restrict__ out)
{
  int tok = blockIdx.x;
  int d0 = threadIdx.x * 8;
  const int* ts = tsl + tok * 8;
  int e0 = ts[0], p0 = ts[1]; float w0 = __int_as_float(ts[2]);
  int e1 = ts[3], p1 = ts[4]; float w1 = __int_as_float(ts[5]);
  int b0 = 0, b1s = 0;
  #pragma unroll
  for (int i = 0; i < E; ++i){
    int c = cnt[i];
    b0  += (i < e0) ? c : 0;
    b1s += (i < e1) ? c : 0;
  }
  bf16x8 y0 = *reinterpret_cast<const bf16x8*>(&yb[((size_t)(b0 + p0)) * D + d0]);
  bf16x8 y1 = *reinterpret_cast<const bf16x8*>(&yb[((size_t)(b1s + p1)) * D + d0]);
  float o[8];
  #pragma unroll
  for (int j = 0; j < 8; ++j)
    o[j] = w0 * b2f((unsigned short)y0[j]) + w1 * b2f((unsigned short)y1[j]);
  *reinterpret_cast<float4*>(&out[(size_t)tok * D + d0])     = *reinterpret_cast<float4*>(&o[0]);
  *reinterpret_cast<float4*>(&out[(size_t)tok * D + d0 + 4]) = *reinterpret_cast<float4*>(&o[4]);
}

extern "C" void kernel_launch(void* const* d_in, const int* in_sizes, int n_in,
                              void* d_out, int out_size, void* d_ws, size_t ws_size,
                              hipStream_t stream)
{
  const float* x  = (const float*)d_in[0];
  const float* u1 = (const float*)d_in[1];
  const float* v1 = (const float*)d_in[2];
  const float* b1 = (const float*)d_in[3];
  const float* u2 = (const float*)d_in[4];
  const float* v2 = (const float*)d_in[5];
  const float* b2 = (const float*)d_in[6];
  const float* gw = (const float*)d_in[7];
  const float* gb = (const float*)d_in[8];
  float* out = (float*)d_out;

  const size_t SZ_XB  = (size_t)NTOK * D * 2;   // 16 MiB
  const size_t SZ_U1P = (size_t)E * R * D * 2;  //  2 MiB
  const size_t SZ_V1P = (size_t)E * H * R * 2;  //  8 MiB
  const size_t SZ_U2P = (size_t)E * R * H * 2;  //  8 MiB
  const size_t SZ_V2P = (size_t)E * D * R * 2;  //  2 MiB
  const size_t SZ_T1  = (size_t)E * NTOK * R * 2;
  const size_t SZ_T2  = (size_t)E * NTOK * R * 4;

  char* ws = (char*)d_ws;
  size_t o = 0;
  auto take = [&](size_t b){ void* p = ws + o; o = (o + b + 255) & ~(size_t)255; return p; };
  int* cnt = (int*)take(E * 4);
  int* lst = (int*)take((size_t)E * NTOK * 4);
  int* tsl = (int*)take((size_t)NTOK * 8 * 4);
  char* A  = (char*)take(SZ_XB + SZ_U1P + SZ_V1P + SZ_U2P);   // 34 MiB
  unsigned short* xb  = (unsigned short*)A;
  unsigned short* u1p = (unsigned short*)(A + SZ_XB);
  unsigned short* v1p = (unsigned short*)(A + SZ_XB + SZ_U1P);
  unsigned short* u2p = (unsigned short*)(A + SZ_XB + SZ_U1P + SZ_V1P);
  unsigned short* yb  = (unsigned short*)A;                   // alias: all dead by out_kernel
  unsigned short* v2p = (unsigned short*)take(SZ_V2P);
  unsigned short* T1buf = (unsigned short*)take(SZ_T1);
  float* T2acc = (float*)take(SZ_T2);

  hipMemsetAsync(cnt, 0, E * 4, stream);
  hipMemsetAsync(T2acc, 0, SZ_T2, stream);

  gate_kernel<<<NTOK / 8, 256, 0, stream>>>(x, gw, gb, tsl, xb);
  route_kernel<<<NTOK / 256, 256, 0, stream>>>(tsl, cnt, lst);
  pack_tr<<<dim3(1, D / 64, E), 256, 0, stream>>>(u1, u1p, D, R);   // -> [r][d]
  pack_tr<<<dim3(H / 64, 1, E), 256, 0, stream>>>(v1, v1p, R, H);   // -> [h][r]
  pack_tr<<<dim3(1, H / 64, E), 256, 0, stream>>>(u2, u2p, H, R);   // -> [r][h]
  pack_tr<<<dim3(D / 64, 1, E), 256, 0, stream>>>(v2, v2p, R, D);   // -> [d][r]

  t1_kernel<<<dim3(NTOK / 64, E), 256, 0, stream>>>(xb, u1p, cnt, lst, T1buf);
  mid_kernel<<<dim3(NTOK / MSLOT, HSPLIT, E), 512, 0, stream>>>(T1buf, v1p, u2p, b1, cnt, T2acc);
  out_kernel<<<dim3(NTOK / 64, E), 512, 0, stream>>>(T2acc, v2p, b2, cnt, yb);
  combine_kernel<<<NTOK, 256, 0, stream>>>(yb, tsl, cnt, out);
}

// Round 9
// 322.781 us; speedup vs baseline: 1.0618x; 1.0618x over previous
//
#include <hip/hip_runtime.h>
#include <hip/hip_bf16.h>

#define E 8
#define D 2048
#define H 8192
#define R 64
#define NTOK 4096
#define HSPLIT 8
#define HPER (H / HSPLIT)   // 1024
#define MSLOT 128           // slots per mid block
#define SH 128              // h subchunk

typedef __attribute__((ext_vector_type(8))) short bf16x8;
typedef __attribute__((ext_vector_type(4))) float f32x4;
typedef __attribute__((ext_vector_type(16))) float f32x16;

__device__ __forceinline__ unsigned short f2b(float f){
  union { __hip_bfloat16 h; unsigned short u; } cv;
  cv.h = __float2bfloat16(f);
  return cv.u;
}
__device__ __forceinline__ float b2f(unsigned short u){
  union { unsigned int i; float f; } cv; cv.i = ((unsigned int)u) << 16; return cv.f;
}

// MFMA 16x16x32 fragment from [row][k] LDS tile
__device__ __forceinline__ bf16x8 ldfrag(const unsigned short* base, int row0, int k0,
                                         int pitch, int lane){
  return *reinterpret_cast<const bf16x8*>(base + (row0 + (lane & 15)) * pitch
                                          + k0 + ((lane >> 4) << 3));
}
// MFMA 32x32x16 fragment from [row][k] LDS tile: lane l -> row row0+(l&31), k k0+(l>>5)*8..+7
__device__ __forceinline__ bf16x8 ldfrag32(const unsigned short* base, int row0, int k0,
                                           int pitch, int lane){
  return *reinterpret_cast<const bf16x8*>(base + (row0 + (lane & 31)) * pitch
                                          + k0 + ((lane >> 5) << 3));
}

// ---------------- transpose-pack: src[e][RS][CS] f32 -> dst[e][CS][RS] bf16 ----------------
__global__ __launch_bounds__(256) void pack_tr(const float* __restrict__ src,
                                               unsigned short* __restrict__ dst,
                                               int RS, int CS){
  int e = blockIdx.z;
  const float* s = src + (size_t)e * RS * CS;
  unsigned short* d = dst + (size_t)e * RS * CS;
  int c0 = blockIdx.x * 64, r0 = blockIdx.y * 64;
  int l = threadIdx.x & 63, cb = (threadIdx.x >> 6) * 16;
  int r = r0 + l;
  const float4* sp = reinterpret_cast<const float4*>(s + (size_t)r * CS + c0 + cb);
  float v[16];
  #pragma unroll
  for (int q = 0; q < 4; ++q){
    float4 t = sp[q];
    v[q*4] = t.x; v[q*4+1] = t.y; v[q*4+2] = t.z; v[q*4+3] = t.w;
  }
  #pragma unroll
  for (int j = 0; j < 16; ++j)
    d[(size_t)(c0 + cb + j) * RS + r] = f2b(v[j]);
}

// ---------------- gate: NO ATOMICS. logits + top2 + weights -> tsl; fused xb pack ----------------
__global__ __launch_bounds__(256) void gate_kernel(
    const float* __restrict__ x, const float* __restrict__ gw,
    const float* __restrict__ gb, int* __restrict__ tsl,
    unsigned short* __restrict__ xb)
{
  int wid  = threadIdx.x >> 6;
  int lane = threadIdx.x & 63;
  int n0 = blockIdx.x * 8 + wid * 2;      // 2 tokens per wave

  float acc[2][E];
  #pragma unroll
  for (int t = 0; t < 2; ++t)
    #pragma unroll
    for (int e = 0; e < E; ++e) acc[t][e] = 0.f;

  for (int i = 0; i < D / 256; ++i){      // 8 iters
    int dd = i * 256 + lane * 4;
    float4 xv[2];
    #pragma unroll
    for (int t = 0; t < 2; ++t){
      xv[t] = *reinterpret_cast<const float4*>(x + (size_t)(n0 + t) * D + dd);
      unsigned short o[4] = { f2b(xv[t].x), f2b(xv[t].y), f2b(xv[t].z), f2b(xv[t].w) };
      *reinterpret_cast<ushort4*>(xb + (size_t)(n0 + t) * D + dd) = *reinterpret_cast<ushort4*>(o);
    }
    #pragma unroll
    for (int e = 0; e < E; ++e){
      float4 g = *reinterpret_cast<const float4*>(gw + (size_t)e * D + dd);
      #pragma unroll
      for (int t = 0; t < 2; ++t)
        acc[t][e] += xv[t].x * g.x + xv[t].y * g.y + xv[t].z * g.z + xv[t].w * g.w;
    }
  }

  #pragma unroll
  for (int t = 0; t < 2; ++t){
    #pragma unroll
    for (int e = 0; e < E; ++e){
      float v = acc[t][e];
      for (int off = 32; off; off >>= 1) v += __shfl_xor(v, off, 64);
      acc[t][e] = v + gb[e];
    }
    if (lane == 0){
      int n = n0 + t;
      float l0 = -1e30f, l1 = -1e30f; int i0 = 0, i1 = 0;
      #pragma unroll
      for (int e = 0; e < E; ++e){
        float v = acc[t][e];
        if (v > l0){ l1 = l0; i1 = i0; l0 = v; i0 = e; }
        else if (v > l1){ l1 = v; i1 = e; }
      }
      float tt = expf(l1 - l0);
      float w0 = 1.f / (1.f + tt);
      float w1 = tt * w0;
      int* ts = tsl + n * 8;
      ts[0] = i0; ts[2] = __float_as_int(w0);
      ts[3] = i1; ts[5] = __float_as_int(w1);
    }
  }
}

// ---------------- route: wave-aggregated slot assignment (512 atomics total) ----------------
__global__ __launch_bounds__(256) void route_kernel(
    int* __restrict__ tsl, int* __restrict__ cnt, int* __restrict__ lst)
{
  int wid  = threadIdx.x >> 6;
  int lane = threadIdx.x & 63;
  int tok  = blockIdx.x * 256 + wid * 64 + lane;
  int* ts = tsl + tok * 8;
  int i0 = ts[0], i1 = ts[3];
  unsigned long long below = (1ULL << lane) - 1ULL;

  #pragma unroll
  for (int e = 0; e < E; ++e){
    unsigned long long m0 = __ballot(i0 == e);
    unsigned long long m1 = __ballot(i1 == e);
    int c0  = __popcll(m0);
    int tot = c0 + __popcll(m1);
    int base = 0;
    if (lane == 0 && tot) base = atomicAdd(&cnt[e], tot);
    base = __shfl(base, 0, 64);
    if (i0 == e){
      int p = base + __popcll(m0 & below);
      lst[e * NTOK + p] = tok;  ts[1] = p;
    }
    if (i1 == e){
      int p = base + c0 + __popcll(m1 & below);
      lst[e * NTOK + p] = tok;  ts[4] = p;
    }
  }
}

// ---------------- T1 = X_gather @ u1[e]  (64-slot tile, 256 thr) ----------------
__global__ __launch_bounds__(256) void t1_kernel(
    const unsigned short* __restrict__ xb, const unsigned short* __restrict__ u1p,
    const int* __restrict__ cnt, const int* __restrict__ lst,
    unsigned short* __restrict__ T1buf)
{
  int e = blockIdx.y;
  int nc = cnt[e];
  int t0 = blockIdx.x * 64;
  if (t0 >= nc) return;

  __shared__ int s_tok[64];
  __shared__ unsigned short Xs[64 * 136];
  __shared__ unsigned short U1s[64 * 136];
  int tid = threadIdx.x, w = tid >> 6, lane = tid & 63;

  if (tid < 64) s_tok[tid] = lst[e * NTOK + min(t0 + tid, nc - 1)];
  __syncthreads();

  int m = (w & 3) * 16;
  f32x4 z = {0.f, 0.f, 0.f, 0.f};
  f32x4 acc[4] = {z, z, z, z};

  for (int kc = 0; kc < D; kc += 128){
    __syncthreads();
    #pragma unroll
    for (int s = 0; s < 4; ++s){
      int id = tid + s * 256;
      int rr = id >> 4, c = (id & 15) * 8;
      *reinterpret_cast<bf16x8*>(&Xs[rr * 136 + c]) =
        *reinterpret_cast<const bf16x8*>(&xb[(size_t)s_tok[rr] * D + kc + c]);
      *reinterpret_cast<bf16x8*>(&U1s[rr * 136 + c]) =
        *reinterpret_cast<const bf16x8*>(&u1p[((size_t)e * R + rr) * D + kc + c]);
    }
    __syncthreads();
    #pragma unroll
    for (int j = 0; j < 4; ++j)
      #pragma unroll
      for (int ks = 0; ks < 4; ++ks)
        acc[j] = __builtin_amdgcn_mfma_f32_16x16x32_bf16(
            ldfrag(Xs, m, ks * 32, 136, lane),
            ldfrag(U1s, j * 16, ks * 32, 136, lane), acc[j], 0, 0, 0);
  }
  #pragma unroll
  for (int j = 0; j < 4; ++j){
    int col = j * 16 + (lane & 15);
    #pragma unroll
    for (int q = 0; q < 4; ++q){
      int row = m + ((lane >> 4) << 2) + q;
      T1buf[((size_t)e * NTOK + t0 + row) * R + col] = f2b(acc[j][q]);
    }
  }
}

// ---------------- mid v4: 32x32x16, T1 in regs, swapped B1 (H^T), 2 barriers, 2 blk/CU ----
__global__ __launch_bounds__(512, 4) void mid_kernel(
    const unsigned short* __restrict__ T1buf, const unsigned short* __restrict__ v1p,
    const unsigned short* __restrict__ u2p, const float* __restrict__ b1,
    const int* __restrict__ cnt, float* __restrict__ T2acc)
{
  int e = blockIdx.z;
  int nc = cnt[e];
  int t0 = blockIdx.x * MSLOT;
  if (t0 >= nc) return;
  int hc0 = blockIdx.y * HPER;

  __shared__ unsigned short v1s[SH * 72];      // [h][r]      18432 B
  __shared__ unsigned short u2s[64 * 136];     // [r][h]      17408 B
  __shared__ unsigned short Hs[MSLOT * 136];   // [slot][h]   34816 B
  __shared__ float b1s[HPER];                  //              4096 B -> 74752 total

  int tid = threadIdx.x, w = tid >> 6, lane = tid & 63;
  int s0 = (w & 3) * 32;        // this wave's slot group
  int hb = (w >> 2) * 64;       // this wave's h-half within subchunk (B1 rows AND B2 k)

  for (int i = tid; i < HPER; i += 512) b1s[i] = b1[(size_t)e * H + hc0 + i];

  // T1 B-fragments in registers: wave's 32 slots x 64 r (loaded once per block)
  bf16x8 t1f[4];
  #pragma unroll
  for (int kc = 0; kc < 4; ++kc)
    t1f[kc] = *reinterpret_cast<const bf16x8*>(
        &T1buf[((size_t)e * NTOK + t0 + s0 + (lane & 31)) * R + kc * 16 + ((lane >> 5) << 3)]);

  f32x16 acc0, acc1;            // T2 partials: [32 slots] x r 0..31 / 32..63
  #pragma unroll
  for (int q = 0; q < 16; ++q){ acc0[q] = 0.f; acc1[q] = 0.f; }

  // register prefetch of subchunk 0 (T14)
  bf16x8 pv[2], pu[2];
  #pragma unroll
  for (int s = 0; s < 2; ++s){
    int id = tid + s * 512;
    pv[s] = *reinterpret_cast<const bf16x8*>(&v1p[((size_t)e * H + hc0 + (id >> 3)) * R + (id & 7) * 8]);
    pu[s] = *reinterpret_cast<const bf16x8*>(&u2p[((size_t)e * R + (id >> 4)) * H + hc0 + (id & 15) * 8]);
  }

  for (int hs = 0; hs < HPER; hs += SH){
    __syncthreads();                           // prev B1/B2 done reading v1s/u2s
    #pragma unroll
    for (int s = 0; s < 2; ++s){
      int id = tid + s * 512;
      *reinterpret_cast<bf16x8*>(&v1s[(id >> 3) * 72 + (id & 7) * 8]) = pv[s];
      *reinterpret_cast<bf16x8*>(&u2s[(id >> 4) * 136 + (id & 15) * 8]) = pu[s];
    }
    __syncthreads();                           // staged

    // B1 (swapped): H^T tile = mfma(A=v1[h][r], B=T1[slot][r]) -> lane: 1 slot-col, 16 h-rows
    int ccol = s0 + (lane & 31);
    #pragma unroll
    for (int tile = 0; tile < 2; ++tile){
      int hT = hb + tile * 32;
      f32x16 hacc;
      #pragma unroll
      for (int q = 0; q < 16; ++q) hacc[q] = 0.f;
      #pragma unroll
      for (int kc = 0; kc < 4; ++kc)
        hacc = __builtin_amdgcn_mfma_f32_32x32x16_bf16(
            ldfrag32(v1s, hT, kc * 16, 72, lane), t1f[kc], hacc, 0, 0, 0);
      #pragma unroll
      for (int g = 0; g < 4; ++g){
        int hw = hT + 8 * g + 4 * (lane >> 5);
        unsigned short o[4];
        #pragma unroll
        for (int j = 0; j < 4; ++j){
          float v = hacc[4 * g + j] + b1s[hs + hw + j];
          o[j] = f2b(v > 0.f ? v : 0.f);
        }
        *reinterpret_cast<ushort4*>(&Hs[ccol * 136 + hw]) = *reinterpret_cast<ushort4*>(o);
      }
    }

    // prefetch next subchunk (overlaps B2)
    int hn = (hs + SH < HPER) ? hs + SH : 0;
    #pragma unroll
    for (int s = 0; s < 2; ++s){
      int id = tid + s * 512;
      pv[s] = *reinterpret_cast<const bf16x8*>(&v1p[((size_t)e * H + hc0 + hn + (id >> 3)) * R + (id & 7) * 8]);
      pu[s] = *reinterpret_cast<const bf16x8*>(&u2p[((size_t)e * R + (id >> 4)) * H + hc0 + hn + (id & 15) * 8]);
    }

    // B2: acc += Hs[s0..+31][hb..+63] @ u2^T — reads EXACTLY this wave's B1 output,
    // no cross-wave dependency -> no barrier needed (lgkmcnt orders own write->read).
    #pragma unroll
    for (int kc = 0; kc < 4; ++kc){
      bf16x8 a = ldfrag32(Hs, s0, hb + kc * 16, 136, lane);
      acc0 = __builtin_amdgcn_mfma_f32_32x32x16_bf16(
          a, ldfrag32(u2s, 0,  hb + kc * 16, 136, lane), acc0, 0, 0, 0);
      acc1 = __builtin_amdgcn_mfma_f32_32x32x16_bf16(
          a, ldfrag32(u2s, 32, hb + kc * 16, 136, lane), acc1, 0, 0, 0);
    }
  }

  int col = lane & 31;
  #pragma unroll
  for (int q = 0; q < 16; ++q){
    int srow = s0 + (q & 3) + 8 * (q >> 2) + 4 * (lane >> 5);
    float* dst = &T2acc[((size_t)e * NTOK + t0 + srow) * R];
    atomicAdd(dst + col,      acc0[q]);
    atomicAdd(dst + col + 32, acc1[q]);
  }
}

// ---------------- out: y[slot] = T2 @ v2[e] + b2  -> compact bf16 yb ----------------
__global__ __launch_bounds__(512, 4) void out_kernel(
    const float* __restrict__ T2acc, const unsigned short* __restrict__ v2p,
    const float* __restrict__ b2, const int* __restrict__ cnt,
    unsigned short* __restrict__ yb)
{
  int e = blockIdx.y;
  int nc = cnt[e];
  int t0 = blockIdx.x * 64;
  if (t0 >= nc) return;
  int base = 0;
  #pragma unroll
  for (int i = 0; i < E; ++i) base += (i < e) ? cnt[i] : 0;

  __shared__ unsigned short T2s[64 * 72];
  __shared__ unsigned short v2s[256 * 72];
  __shared__ float b2s[D];
  int tid = threadIdx.x, w = tid >> 6, lane = tid & 63;

  { int rr = tid >> 3, c = (tid & 7) * 8;
    const float* src = &T2acc[((size_t)e * NTOK + t0 + rr) * R + c];
    float4 a = *reinterpret_cast<const float4*>(src);
    float4 b = *reinterpret_cast<const float4*>(src + 4);
    unsigned short o[8] = { f2b(a.x), f2b(a.y), f2b(a.z), f2b(a.w),
                            f2b(b.x), f2b(b.y), f2b(b.z), f2b(b.w) };
    *reinterpret_cast<bf16x8*>(&T2s[rr * 72 + c]) = *reinterpret_cast<bf16x8*>(o); }
  for (int i = tid; i < D; i += 512) b2s[i] = b2[(size_t)e * D + i];

  int m1 = (w & 1) * 32, nb = (w >> 1) * 64;
  f32x4 z = {0.f, 0.f, 0.f, 0.f};

  for (int dc = 0; dc < D; dc += 256){
    __syncthreads();
    #pragma unroll
    for (int s = 0; s < 4; ++s){
      int id = tid + s * 512;
      int rr = id >> 3, c = (id & 7) * 8;
      *reinterpret_cast<bf16x8*>(&v2s[rr * 72 + c]) =
        *reinterpret_cast<const bf16x8*>(&v2p[((size_t)e * D + dc + rr) * R + c]);
    }
    __syncthreads();
    #pragma unroll
    for (int i = 0; i < 2; ++i)
      #pragma unroll
      for (int j = 0; j < 4; ++j){
        f32x4 a = z;
        #pragma unroll
        for (int ks = 0; ks < 2; ++ks)
          a = __builtin_amdgcn_mfma_f32_16x16x32_bf16(
              ldfrag(T2s, m1 + i * 16, ks * 32, 72, lane),
              ldfrag(v2s, nb + j * 16, ks * 32, 72, lane), a, 0, 0, 0);
        int dcol = dc + nb + j * 16 + (lane & 15);
        float bv = b2s[dcol];
        #pragma unroll
        for (int q = 0; q < 4; ++q){
          int row = m1 + i * 16 + ((lane >> 4) << 2) + q;
          if (t0 + row < nc)
            yb[((size_t)(base + t0 + row)) * D + dcol] = f2b(a[q] + bv);
        }
      }
  }
}

// ---------------- combine: out[tok] = w0*y[g0] + w1*y[g1] ----------------
__global__ __launch_bounds__(256) void combine_kernel(
    const unsigned short* __restrict__ yb, const int* __restrict__ tsl,
    const int* __restrict__ cnt, float* __restrict__ out)
{
  int tok = blockIdx.x;
  int d0 = threadIdx.x * 8;
  const int* ts = tsl + tok * 8;
  int e0 = ts[0], p0 = ts[1]; float w0 = __int_as_float(ts[2]);
  int e1 = ts[3], p1 = ts[4]; float w1 = __int_as_float(ts[5]);
  int b0 = 0, b1s = 0;
  #pragma unroll
  for (int i = 0; i < E; ++i){
    int c = cnt[i];
    b0  += (i < e0) ? c : 0;
    b1s += (i < e1) ? c : 0;
  }
  bf16x8 y0 = *reinterpret_cast<const bf16x8*>(&yb[((size_t)(b0 + p0)) * D + d0]);
  bf16x8 y1 = *reinterpret_cast<const bf16x8*>(&yb[((size_t)(b1s + p1)) * D + d0]);
  float o[8];
  #pragma unroll
  for (int j = 0; j < 8; ++j)
    o[j] = w0 * b2f((unsigned short)y0[j]) + w1 * b2f((unsigned short)y1[j]);
  *reinterpret_cast<float4*>(&out[(size_t)tok * D + d0])     = *reinterpret_cast<float4*>(&o[0]);
  *reinterpret_cast<float4*>(&out[(size_t)tok * D + d0 + 4]) = *reinterpret_cast<float4*>(&o[4]);
}

extern "C" void kernel_launch(void* const* d_in, const int* in_sizes, int n_in,
                              void* d_out, int out_size, void* d_ws, size_t ws_size,
                              hipStream_t stream)
{
  const float* x  = (const float*)d_in[0];
  const float* u1 = (const float*)d_in[1];
  const float* v1 = (const float*)d_in[2];
  const float* b1 = (const float*)d_in[3];
  const float* u2 = (const float*)d_in[4];
  const float* v2 = (const float*)d_in[5];
  const float* b2 = (const float*)d_in[6];
  const float* gw = (const float*)d_in[7];
  const float* gb = (const float*)d_in[8];
  float* out = (float*)d_out;

  const size_t SZ_XB  = (size_t)NTOK * D * 2;   // 16 MiB
  const size_t SZ_U1P = (size_t)E * R * D * 2;  //  2 MiB
  const size_t SZ_V1P = (size_t)E * H * R * 2;  //  8 MiB
  const size_t SZ_U2P = (size_t)E * R * H * 2;  //  8 MiB
  const size_t SZ_V2P = (size_t)E * D * R * 2;  //  2 MiB
  const size_t SZ_T1  = (size_t)E * NTOK * R * 2;
  const size_t SZ_T2  = (size_t)E * NTOK * R * 4;

  char* ws = (char*)d_ws;
  size_t o = 0;
  auto take = [&](size_t b){ void* p = ws + o; o = (o + b + 255) & ~(size_t)255; return p; };
  int* cnt = (int*)take(E * 4);
  int* lst = (int*)take((size_t)E * NTOK * 4);
  int* tsl = (int*)take((size_t)NTOK * 8 * 4);
  char* A  = (char*)take(SZ_XB + SZ_U1P + SZ_V1P + SZ_U2P);   // 34 MiB
  unsigned short* xb  = (unsigned short*)A;
  unsigned short* u1p = (unsigned short*)(A + SZ_XB);
  unsigned short* v1p = (unsigned short*)(A + SZ_XB + SZ_U1P);
  unsigned short* u2p = (unsigned short*)(A + SZ_XB + SZ_U1P + SZ_V1P);
  unsigned short* yb  = (unsigned short*)A;                   // alias: all dead by out_kernel
  unsigned short* v2p = (unsigned short*)take(SZ_V2P);
  unsigned short* T1buf = (unsigned short*)take(SZ_T1);
  float* T2acc = (float*)take(SZ_T2);

  hipMemsetAsync(cnt, 0, E * 4, stream);
  hipMemsetAsync(T2acc, 0, SZ_T2, stream);

  gate_kernel<<<NTOK / 8, 256, 0, stream>>>(x, gw, gb, tsl, xb);
  route_kernel<<<NTOK / 256, 256, 0, stream>>>(tsl, cnt, lst);
  pack_tr<<<dim3(1, D / 64, E), 256, 0, stream>>>(u1, u1p, D, R);   // -> [r][d]
  pack_tr<<<dim3(H / 64, 1, E), 256, 0, stream>>>(v1, v1p, R, H);   // -> [h][r]
  pack_tr<<<dim3(1, H / 64, E), 256, 0, stream>>>(u2, u2p, H, R);   // -> [r][h]
  pack_tr<<<dim3(D / 64, 1, E), 256, 0, stream>>>(v2, v2p, R, D);   // -> [d][r]

  t1_kernel<<<dim3(NTOK / 64, E), 256, 0, stream>>>(xb, u1p, cnt, lst, T1buf);
  mid_kernel<<<dim3(NTOK / MSLOT, HSPLIT, E), 512, 0, stream>>>(T1buf, v1p, u2p, b1, cnt, T2acc);
  out_kernel<<<dim3(NTOK / 64, E), 512, 0, stream>>>(T2acc, v2p, b2, cnt, yb);
  combine_kernel<<<NTOK, 256, 0, stream>>>(yb, tsl, cnt, out);
}